// Round 3
// baseline (1037.416 us; speedup 1.0000x reference)
//
#include <hip/hip_runtime.h>

typedef _Float16 f16;
typedef _Float16 f16x8 __attribute__((ext_vector_type(8)));
typedef float f32x4 __attribute__((ext_vector_type(4)));

#define BS 65536
#define D 768
#define H 12
#define BM 128
#define BK 32
#define KITERS 24   // 768/32
#define ES 208      // epilogue row stride (192 + 16 pad), f16 elems

// Fully fused: LN (in-block, registers) + QKV GEMM (f16 MFMA) + 2x2 attention + residual.
// All global I/O is FP32 (per reference); f16 only as internal MFMA operand format.
// grid: (BS/BM)*H blocks, h fastest. block: 512 threads (8 waves).
// Block (rb,h): rows [rb*128, rb*128+128), head h -> writes out[rows][h*64 .. h*64+64).
__global__ __launch_bounds__(512) void fused_kernel(const float* __restrict__ x,
                                                    const float* __restrict__ Wq,
                                                    const float* __restrict__ Wk,
                                                    const float* __restrict__ Wv,
                                                    const float* __restrict__ gamma,
                                                    const float* __restrict__ beta,
                                                    float* __restrict__ out) {
    __shared__ f16 sA[BM * BK]  __attribute__((aligned(16)));  // 8 KB
    __shared__ f16 sB[192 * BK] __attribute__((aligned(16)));  // 12 KB
    __shared__ f16 sE[BM * ES]  __attribute__((aligned(16)));  // 53 KB epilogue q,k,v

    int tid  = threadIdx.x;
    int wave = tid >> 6;
    int lane = tid & 63;
    int h    = blockIdx.x % H;
    int rb   = blockIdx.x / H;
    size_t row_base = (size_t)rb * BM;

    int r   = tid >> 2;  // 0..127: the A-row this thread owns (stats + staging)
    int sub = tid & 3;   // quad index within the row

    // ---- Phase 0: LayerNorm stats for row r (4 lanes per row, 192 elems each) ----
    const float4* xr4 = (const float4*)(x + (row_base + r) * D) + sub * 48;
    float sum = 0.f, sq = 0.f;
#pragma unroll 8
    for (int j = 0; j < 48; ++j) {
        float4 w = xr4[j];
        sum += w.x + w.y + w.z + w.w;
        sq  += w.x * w.x + w.y * w.y + w.z * w.z + w.w * w.w;
    }
    // quad lanes of a row are 4 consecutive lanes of one wave (xor 1,2 stays in quad)
    sum += __shfl_xor(sum, 1, 64); sum += __shfl_xor(sum, 2, 64);
    sq  += __shfl_xor(sq,  1, 64); sq  += __shfl_xor(sq,  2, 64);
    float mu   = sum * (1.0f / D);
    float rstd = rsqrtf(sq * (1.0f / D) - mu * mu + 1e-6f);

    // ---- staging source pointers ----
    // A chunk per thread: row r, k-octet sub (8 fp32 -> 8 f16, one 16B ds_write)
    const float* a_src = x + (row_base + r) * D + sub * 8;
    // B chunk c = tid: feature row n=c>>2 of [q(0..63)|k(64..127)], k-octet c&3.
    int n1 = tid >> 2;
    const float* W1 = (n1 < 64) ? Wq : Wk;
    const float* b1 = W1 + ((size_t)h * 64 + (n1 & 63)) * D + (tid & 3) * 8;
    const float* b2 = Wv + ((size_t)h * 64 + (tid >> 2)) * D + (tid & 3) * 8;  // tid<256 only

    const int laneM = lane & 15;
    const int laneK = lane >> 4;

    f32x4 acc[12];
#pragma unroll
    for (int t = 0; t < 12; ++t) acc[t] = (f32x4){0.f, 0.f, 0.f, 0.f};

    for (int ko = 0; ko < KITERS; ++ko) {
        int koff = ko * BK;
        // A: load raw fp32 x, normalize, convert to f16, stage (16B ds_write)
        float4 xa0 = *(const float4*)(a_src + koff);
        float4 xa1 = *(const float4*)(a_src + koff + 4);
        float4 g0  = *(const float4*)(gamma + koff + sub * 8);
        float4 g1  = *(const float4*)(gamma + koff + sub * 8 + 4);
        float4 be0 = *(const float4*)(beta  + koff + sub * 8);
        float4 be1 = *(const float4*)(beta  + koff + sub * 8 + 4);
        f16x8 an;
        an[0] = (f16)((xa0.x - mu) * rstd * g0.x + be0.x);
        an[1] = (f16)((xa0.y - mu) * rstd * g0.y + be0.y);
        an[2] = (f16)((xa0.z - mu) * rstd * g0.z + be0.z);
        an[3] = (f16)((xa0.w - mu) * rstd * g0.w + be0.w);
        an[4] = (f16)((xa1.x - mu) * rstd * g1.x + be1.x);
        an[5] = (f16)((xa1.y - mu) * rstd * g1.y + be1.y);
        an[6] = (f16)((xa1.z - mu) * rstd * g1.z + be1.z);
        an[7] = (f16)((xa1.w - mu) * rstd * g1.w + be1.w);
        *(f16x8*)(sA + r * BK + sub * 8) = an;

        // B: fp32 load -> f16 -> 16B ds_write (chunk c lands at sB + c*8 elems)
        float4 w0 = *(const float4*)(b1 + koff);
        float4 w1 = *(const float4*)(b1 + koff + 4);
        f16x8 bn;
        bn[0] = (f16)w0.x; bn[1] = (f16)w0.y; bn[2] = (f16)w0.z; bn[3] = (f16)w0.w;
        bn[4] = (f16)w1.x; bn[5] = (f16)w1.y; bn[6] = (f16)w1.z; bn[7] = (f16)w1.w;
        *(f16x8*)(sB + tid * 8) = bn;
        if (tid < 256) {
            float4 v0 = *(const float4*)(b2 + koff);
            float4 v1 = *(const float4*)(b2 + koff + 4);
            f16x8 vn;
            vn[0] = (f16)v0.x; vn[1] = (f16)v0.y; vn[2] = (f16)v0.z; vn[3] = (f16)v0.w;
            vn[4] = (f16)v1.x; vn[5] = (f16)v1.y; vn[6] = (f16)v1.z; vn[7] = (f16)v1.w;
            *(f16x8*)(sB + (512 + tid) * 8) = vn;
        }
        __syncthreads();  // staging visible to all waves

        f16x8 a = *(const f16x8*)(sA + (wave * 16 + laneM) * BK + laneK * 8);
#pragma unroll
        for (int t = 0; t < 12; ++t) {
            f16x8 b = *(const f16x8*)(sB + (t * 16 + laneM) * BK + laneK * 8);
            acc[t] = __builtin_amdgcn_mfma_f32_16x16x32_f16(a, b, acc[t], 0, 0, 0);
        }
        __syncthreads();  // frag reads done before next iteration's staging
    }

    // ---- Epilogue: stage q,k,v to sE (C/D layout: col=lane&15, row=(lane>>4)*4+reg) ----
#pragma unroll
    for (int t = 0; t < 12; ++t) {
        int col = t * 16 + laneM;
        int r0  = wave * 16 + (lane >> 4) * 4;
#pragma unroll
        for (int rr = 0; rr < 4; ++rr)
            sE[(r0 + rr) * ES + col] = (f16)acc[t][rr];
    }
    // wave-local from here: each wave reads only rows it wrote itself.

    int erow = lane >> 2;  // 0..15
    int esub = lane & 3;   // dk octet (8 elems)
    const f16* Er = sE + (wave * 16 + erow) * ES;

    f16x8 qr0 = *(const f16x8*)(Er + 0   + esub * 8);
    f16x8 qr1 = *(const f16x8*)(Er + 32  + esub * 8);
    f16x8 kr0 = *(const f16x8*)(Er + 64  + esub * 8);
    f16x8 kr1 = *(const f16x8*)(Er + 96  + esub * 8);
    f16x8 vr0 = *(const f16x8*)(Er + 128 + esub * 8);
    f16x8 vr1 = *(const f16x8*)(Er + 160 + esub * 8);

    float s00 = 0.f, s01 = 0.f, s10 = 0.f, s11 = 0.f;
#pragma unroll
    for (int i = 0; i < 8; ++i) {
        float q0 = (float)qr0[i], q1 = (float)qr1[i];
        float k0 = (float)kr0[i], k1 = (float)kr1[i];
        s00 += q0 * k0; s01 += q0 * k1;
        s10 += q1 * k0; s11 += q1 * k1;
    }
    s00 += __shfl_xor(s00, 1, 64); s00 += __shfl_xor(s00, 2, 64);
    s01 += __shfl_xor(s01, 1, 64); s01 += __shfl_xor(s01, 2, 64);
    s10 += __shfl_xor(s10, 1, 64); s10 += __shfl_xor(s10, 2, 64);
    s11 += __shfl_xor(s11, 1, 64); s11 += __shfl_xor(s11, 2, 64);

    const float scale = 0.17677669529663687f;  // 1/sqrt(32)
    s00 *= scale; s01 *= scale; s10 *= scale; s11 *= scale;

    float m0 = fmaxf(s00, s01);
    float e00 = __expf(s00 - m0), e01 = __expf(s01 - m0);
    float d0 = 1.0f / (e00 + e01);
    float a00 = e00 * d0, a01 = e01 * d0;
    float m1 = fmaxf(s10, s11);
    float e10 = __expf(s10 - m1), e11 = __expf(s11 - m1);
    float d1 = 1.0f / (e10 + e11);
    float a10 = e10 * d1, a11 = e11 * d1;

    size_t grow = row_base + wave * 16 + erow;
    size_t cb   = (size_t)h * 64 + esub * 8;
    const float* xp = x + grow * D + cb;
    float*       op = out + grow * D + cb;

    float4 xv0 = *(const float4*)(xp);
    float4 xv1 = *(const float4*)(xp + 4);
    float4 xv2 = *(const float4*)(xp + 32);
    float4 xv3 = *(const float4*)(xp + 36);
    float4 o0, o1, o2, o3;
    {
        float v0, v1;
        v0 = (float)vr0[0]; v1 = (float)vr1[0]; o0.x = a00 * v0 + a01 * v1 + xv0.x; o2.x = a10 * v0 + a11 * v1 + xv2.x;
        v0 = (float)vr0[1]; v1 = (float)vr1[1]; o0.y = a00 * v0 + a01 * v1 + xv0.y; o2.y = a10 * v0 + a11 * v1 + xv2.y;
        v0 = (float)vr0[2]; v1 = (float)vr1[2]; o0.z = a00 * v0 + a01 * v1 + xv0.z; o2.z = a10 * v0 + a11 * v1 + xv2.z;
        v0 = (float)vr0[3]; v1 = (float)vr1[3]; o0.w = a00 * v0 + a01 * v1 + xv0.w; o2.w = a10 * v0 + a11 * v1 + xv2.w;
        v0 = (float)vr0[4]; v1 = (float)vr1[4]; o1.x = a00 * v0 + a01 * v1 + xv1.x; o3.x = a10 * v0 + a11 * v1 + xv3.x;
        v0 = (float)vr0[5]; v1 = (float)vr1[5]; o1.y = a00 * v0 + a01 * v1 + xv1.y; o3.y = a10 * v0 + a11 * v1 + xv3.y;
        v0 = (float)vr0[6]; v1 = (float)vr1[6]; o1.z = a00 * v0 + a01 * v1 + xv1.z; o3.z = a10 * v0 + a11 * v1 + xv3.z;
        v0 = (float)vr0[7]; v1 = (float)vr1[7]; o1.w = a00 * v0 + a01 * v1 + xv1.w; o3.w = a10 * v0 + a11 * v1 + xv3.w;
    }
    *(float4*)(op)      = o0;
    *(float4*)(op + 4)  = o1;
    *(float4*)(op + 32) = o2;
    *(float4*)(op + 36) = o3;
}

extern "C" void kernel_launch(void* const* d_in, const int* in_sizes, int n_in,
                              void* d_out, int out_size, void* d_ws, size_t ws_size,
                              hipStream_t stream) {
    const float* x     = (const float*)d_in[0];
    const float* Wq    = (const float*)d_in[1];
    const float* Wk    = (const float*)d_in[2];
    const float* Wv    = (const float*)d_in[3];
    const float* gamma = (const float*)d_in[4];
    const float* beta  = (const float*)d_in[5];
    float* out = (float*)d_out;
    (void)d_ws; (void)ws_size;  // no workspace: fully fused, nothing persisted

    fused_kernel<<<dim3((BS / BM) * H), dim3(512), 0, stream>>>(x, Wq, Wk, Wv, gamma, beta, out);
}